// Round 4
// baseline (714.795 us; speedup 1.0000x reference)
//
#include <hip/hip_runtime.h>
#include <stdint.h>

// ---------------- constants ----------------
#define N_NODES 200000
#define DIM     128
#define N_EDGES 1024
#define NNZ_C   1600000
#define NT_TILES 6250        // N_NODES / 32 exactly

// CSR-build binning
#define NBLK   250           // histogram/scatter blocks
#define CHUNK  6400          // NNZ / NBLK
#define ITERS  25            // CHUNK / 256
#define NCB    196           // coarse node buckets of 1024 nodes

// node_gather: wave-per-node-chunk direct-L2 gather
#define NG_BLOCKS 2048
#define NG_WAVES  (NG_BLOCKS*4)   // 8192 waves = exactly one full residency

typedef __attribute__((ext_vector_type(8))) short short8;   // 8 bf16 (4 VGPRs)
typedef __attribute__((ext_vector_type(4))) float f32x4;

__device__ __forceinline__ float u2f(uint32_t u){ union{uint32_t u;float f;} x; x.u=u; return x.f; }
__device__ __forceinline__ uint32_t f2u(float f){ union{uint32_t u;float f;} x; x.f=f; return x.u; }
__device__ __forceinline__ unsigned short f2bf(float f){
  uint32_t u = f2u(f);
  u += 0x7fffu + ((u >> 16) & 1u);      // RNE
  return (unsigned short)(u >> 16);
}

// ---------------- weight prep ----------------
__global__ void prep_tb_w(const float* __restrict__ W, short* __restrict__ Wt){
  int i = blockIdx.x*256 + threadIdx.x;
  if (i >= 5*384*128) return;
  int k   = i & 127;
  int col = (i >> 7) % 384;
  int s   = i / 49152;
  int j = col >> 7, n = col & 127;
  Wt[i] = (short)f2bf(W[((s*3 + j)*128 + k)*128 + n]);
}
// hgW fp32 transposed: Wtf[g][n][k] = W[g][k][n]
__global__ void prep_hg_wf(const float* __restrict__ W, float* __restrict__ Wtf){
  int i = blockIdx.x*256 + threadIdx.x;
  if (i >= 2*128*128) return;
  int k = i & 127;
  int n = (i >> 7) & 127;
  int g = i >> 14;
  Wtf[i] = W[(g*128 + k)*128 + n];
}

// ---------------- CSR build: deterministic binned counting sort ----------------
__global__ __launch_bounds__(256) void hist_kernel(
    const int* __restrict__ nidx, const int* __restrict__ eidx,
    int* __restrict__ ebh, int* __restrict__ nbh)
{
  __shared__ int eh[N_EDGES];
  __shared__ int nh[NCB];
  int tid = threadIdx.x, blk = blockIdx.x;
  #pragma unroll
  for (int l = tid; l < N_EDGES; l += 256) eh[l] = 0;
  for (int l = tid; l < NCB; l += 256) nh[l] = 0;
  __syncthreads();
  int base = blk*CHUNK;
  for (int it = 0; it < ITERS; it++){
    int i = base + it*256 + tid;
    atomicAdd(&eh[eidx[i]], 1);
    atomicAdd(&nh[nidx[i] >> 10], 1);
  }
  __syncthreads();
  for (int l = tid; l < N_EDGES; l += 256) ebh[blk*N_EDGES + l] = eh[l];
  for (int l = tid; l < NCB; l += 256) nbh[blk*NCB + l] = nh[l];
}

__global__ __launch_bounds__(1024) void escan_kernel(
    int* __restrict__ ebh, int* __restrict__ eoff)
{
  __shared__ int sc[1024];
  int e = threadIdx.x;
  int total = 0;
  #pragma unroll 10
  for (int b = 0; b < NBLK; b++){
    int idx = b*N_EDGES + e;
    int t = ebh[idx];
    ebh[idx] = total;
    total += t;
  }
  sc[e] = total; __syncthreads();
  for (int off=1; off<1024; off<<=1){
    int v = (e >= off) ? sc[e-off] : 0;
    __syncthreads();
    sc[e] += v;
    __syncthreads();
  }
  int base = sc[e] - total;   // exclusive
  eoff[e] = base;
  if (e == 1023) eoff[1024] = sc[1023];
  #pragma unroll 10
  for (int b = 0; b < NBLK; b++) ebh[b*N_EDGES + e] += base;
}

__global__ __launch_bounds__(256) void nscan_kernel(
    int* __restrict__ nbh, int* __restrict__ cbase)
{
  __shared__ int sc[256];
  int c = threadIdx.x;
  int total = 0;
  if (c < NCB){
    #pragma unroll 10
    for (int b = 0; b < NBLK; b++){
      int idx = b*NCB + c;
      int t = nbh[idx];
      nbh[idx] = total;
      total += t;
    }
  }
  sc[c] = (c < NCB) ? total : 0; __syncthreads();
  for (int off=1; off<256; off<<=1){
    int v = (c >= off) ? sc[c-off] : 0;
    __syncthreads();
    sc[c] += v;
    __syncthreads();
  }
  int base = sc[c] - ((c < NCB) ? total : 0);
  if (c < NCB) cbase[c] = base;
  if (c == NCB-1) cbase[NCB] = sc[c];
  __syncthreads();
  if (c < NCB){
    #pragma unroll 10
    for (int b = 0; b < NBLK; b++) nbh[b*NCB + c] += base;
  }
}

__global__ __launch_bounds__(256) void scatter_kernel(
    const int* __restrict__ nidx, const int* __restrict__ eidx,
    const int* __restrict__ ebh, const int* __restrict__ nbh,
    int* __restrict__ enodes, uint32_t* __restrict__ pairs)
{
  __shared__ int cure[N_EDGES];
  __shared__ int curn[NCB];
  int tid = threadIdx.x, blk = blockIdx.x;
  for (int l = tid; l < N_EDGES; l += 256) cure[l] = ebh[blk*N_EDGES + l];
  for (int l = tid; l < NCB; l += 256)     curn[l] = nbh[blk*NCB + l];
  __syncthreads();
  int base = blk*CHUNK;
  for (int it = 0; it < ITERS; it++){
    int i = base + it*256 + tid;
    int v = nidx[i], e = eidx[i];
    int pe = atomicAdd(&cure[e], 1);
    enodes[pe] = v;
    int pn = atomicAdd(&curn[v >> 10], 1);
    pairs[pn] = ((uint32_t)v << 10) | (uint32_t)e;
  }
}

__global__ __launch_bounds__(256) void node_build_kernel(
    const uint32_t* __restrict__ pairs, const int* __restrict__ cbase,
    int* __restrict__ noff, int* __restrict__ nedges)
{
  __shared__ int cnt[1024];
  __shared__ int off[1024];
  __shared__ int part[256];
  int tid = threadIdx.x, c = blockIdx.x;
  int n0 = c << 10;
  int nloc = min(1024, N_NODES - n0);
  int s = cbase[c], e = cbase[c+1];
  #pragma unroll
  for (int l = tid; l < 1024; l += 256) cnt[l] = 0;
  __syncthreads();
  for (int i = s + tid; i < e; i += 256)
    atomicAdd(&cnt[(pairs[i] >> 10) & 1023], 1);
  __syncthreads();
  int c0 = cnt[tid*4], c1 = cnt[tid*4+1], c2 = cnt[tid*4+2], c3 = cnt[tid*4+3];
  int sum = c0+c1+c2+c3;
  part[tid] = sum; __syncthreads();
  for (int o=1; o<256; o<<=1){
    int v = (tid >= o) ? part[tid-o] : 0;
    __syncthreads();
    part[tid] += v;
    __syncthreads();
  }
  int pb = part[tid] - sum;
  off[tid*4]   = pb;
  off[tid*4+1] = pb + c0;
  off[tid*4+2] = pb + c0 + c1;
  off[tid*4+3] = pb + c0 + c1 + c2;
  __syncthreads();
  for (int l = tid; l < nloc; l += 256) noff[n0 + l] = s + off[l];
  if (c == 0 && tid == 0) noff[N_NODES] = NNZ_C;
  __syncthreads();
  for (int i = s + tid; i < e; i += 256){
    uint32_t p = pairs[i];
    int local = (p >> 10) & 1023;
    int pos = s + atomicAdd(&off[local], 1);
    nedges[pos] = (int)((p & 1023) << 6);   // pre-scaled: u32-row offset of edge in mbf
  }
}

// ---------------- GEMM: [N,128] @ [128, 3*128], MFMA 16x16x32 bf16 ----------------
// OUT_MODE: 0 = bf16, 1 = f32, 2 = fp8(e4m3)
template<bool IN_F32, int OUT_MODE>
__global__ __launch_bounds__(256, 2) void gemm_kernel(
    const void* __restrict__ in, void* __restrict__ out,
    const short* __restrict__ Wt, const float* __restrict__ bias)
{
  __shared__ short Atile[32][136];
  const int tid  = threadIdx.x;
  const int lane = tid & 63;
  const int w    = tid >> 6;
  const int l15  = lane & 15;
  const int quad = lane >> 4;

  short8 bfrag[3][2][4];
  #pragma unroll
  for (int j = 0; j < 3; j++)
    #pragma unroll
    for (int nt = 0; nt < 2; nt++){
      const short* bp = Wt + (j*128 + w*32 + nt*16 + l15)*128 + quad*8;
      #pragma unroll
      for (int ks = 0; ks < 4; ks++)
        bfrag[j][nt][ks] = *(const short8*)(bp + ks*32);
    }

  float bv[3][2];
  #pragma unroll
  for (int j = 0; j < 3; j++)
    #pragma unroll
    for (int nt = 0; nt < 2; nt++)
      bv[j][nt] = bias[j*128 + w*32 + nt*16 + l15];

  const int arow = tid >> 3;
  const int aseg = (tid & 7) * 2;

  short8 pre0, pre1;
  auto loadA = [&](int t){
    int off = (t*32 + arow)*128 + aseg*8;
    if (IN_F32){
      const float* f = (const float*)in + off;
      f32x4 q0 = ((const f32x4*)f)[0];
      f32x4 q1 = ((const f32x4*)f)[1];
      f32x4 q2 = ((const f32x4*)f)[2];
      f32x4 q3 = ((const f32x4*)f)[3];
      short8 t0, t1;
      #pragma unroll
      for (int u = 0; u < 4; u++){
        t0[u]   = (short)f2bf(q0[u]);
        t0[u+4] = (short)f2bf(q1[u]);
        t1[u]   = (short)f2bf(q2[u]);
        t1[u+4] = (short)f2bf(q3[u]);
      }
      pre0 = t0; pre1 = t1;
    } else {
      const short* hp = (const short*)in + off;
      pre0 = *(const short8*)hp;
      pre1 = *(const short8*)(hp + 8);
    }
  };

  int t = blockIdx.x;
  loadA(t);
  for (;;){
    __syncthreads();
    *(short8*)&Atile[arow][aseg*8]     = pre0;
    *(short8*)&Atile[arow][aseg*8 + 8] = pre1;
    __syncthreads();
    int tn = t + gridDim.x;
    if (tn < NT_TILES) loadA(tn);

    const int base = t*32;
    #pragma unroll
    for (int rt = 0; rt < 2; rt++){
      short8 af[4];
      #pragma unroll
      for (int ks = 0; ks < 4; ks++)
        af[ks] = *(const short8*)&Atile[rt*16 + l15][ks*32 + quad*8];

      f32x4 acc[3][2];
      #pragma unroll
      for (int j = 0; j < 3; j++)
        #pragma unroll
        for (int nt = 0; nt < 2; nt++){
          acc[j][nt] = (f32x4){0.f, 0.f, 0.f, 0.f};
          #pragma unroll
          for (int ks = 0; ks < 4; ks++)
            acc[j][nt] = __builtin_amdgcn_mfma_f32_16x16x32_bf16(
                af[ks], bfrag[j][nt][ks], acc[j][nt], 0, 0, 0);
        }

      #pragma unroll
      for (int nt = 0; nt < 2; nt++){
        int col = w*32 + nt*16 + l15;
        #pragma unroll
        for (int r = 0; r < 4; r++){
          int row = base + rt*16 + quad*4 + r;
          float c2 = acc[1][nt][r] + bv[1][nt];
          float sg = 1.f / (1.f + __expf(-c2));
          float v = acc[0][nt][r] + bv[0][nt] + sg + acc[2][nt][r] + bv[2][nt];
          v = fmaxf(v, 0.f);
          if (OUT_MODE == 1) ((float*)out)[row*128 + col] = v;
          else if (OUT_MODE == 0) ((unsigned short*)out)[row*128 + col] = f2bf(v);
          else {
            int pk = __builtin_amdgcn_cvt_pk_fp8_f32(v, v, 0, false);
            ((unsigned char*)out)[row*128 + col] = (unsigned char)(pk & 0xff);
          }
        }
      }
    }
    if (tn >= NT_TILES) break;
    t = tn;
  }
}

// ---------------- edge gather-sum of fp8 h: s_e[e] = sum_{v in e} h8[v] ----------------
// One block per edge; 8 lanes x 16 B per row, 32 row-slots; 4-deep pipeline.
__device__ __forceinline__ void acc16(float* a, uint4 r){
  uint32_t w[4] = {r.x, r.y, r.z, r.w};
  #pragma unroll
  for (int q = 0; q < 4; q++){
    auto lo = __builtin_amdgcn_cvt_pk_f32_fp8(w[q], false);
    auto hi = __builtin_amdgcn_cvt_pk_f32_fp8(w[q], true);
    a[q*4+0] += lo[0]; a[q*4+1] += lo[1]; a[q*4+2] += hi[0]; a[q*4+3] += hi[1];
  }
}

__global__ __launch_bounds__(256) void edge_gather_kernel(
    const unsigned char* __restrict__ h8, const int* __restrict__ eoff,
    const int* __restrict__ enodes, float* __restrict__ s_e)
{
  int e = blockIdx.x;
  int s = eoff[e], en = eoff[e+1];
  int tid  = threadIdx.x;
  int slot = tid >> 3;          // 32 row-slots
  int ch   = tid & 7;           // 16 B per lane
  const size_t choff = (size_t)ch * 16;

  float a[16];
  #pragma unroll
  for (int j = 0; j < 16; j++) a[j] = 0.f;

  int i0 = s + slot;
  int n0 = (i0      < en) ? enodes[i0]      : -1;
  int n1 = (i0 + 32 < en) ? enodes[i0 + 32] : -1;
  int n2 = (i0 + 64 < en) ? enodes[i0 + 64] : -1;
  int n3 = (i0 + 96 < en) ? enodes[i0 + 96] : -1;

  while (i0 < en){
    int i1 = i0 + 128;
    int m0 = (i1      < en) ? enodes[i1]      : -1;
    int m1 = (i1 + 32 < en) ? enodes[i1 + 32] : -1;
    int m2 = (i1 + 64 < en) ? enodes[i1 + 64] : -1;
    int m3 = (i1 + 96 < en) ? enodes[i1 + 96] : -1;

    uint4 r0 = *(const uint4*)(h8 + (((size_t)max(n0,0)) << 7) + choff);
    uint4 r1 = *(const uint4*)(h8 + (((size_t)max(n1,0)) << 7) + choff);
    uint4 r2 = *(const uint4*)(h8 + (((size_t)max(n2,0)) << 7) + choff);
    uint4 r3 = *(const uint4*)(h8 + (((size_t)max(n3,0)) << 7) + choff);
    if (n0 < 0) r0 = make_uint4(0,0,0,0);
    if (n1 < 0) r1 = make_uint4(0,0,0,0);
    if (n2 < 0) r2 = make_uint4(0,0,0,0);
    if (n3 < 0) r3 = make_uint4(0,0,0,0);

    acc16(a, r0); acc16(a, r1); acc16(a, r2); acc16(a, r3);

    n0 = m0; n1 = m1; n2 = m2; n3 = m3;
    i0 = i1;
  }

  __shared__ float red[32][132];
  #pragma unroll
  for (int j = 0; j < 16; j++) red[slot][ch*16 + j] = a[j];
  __syncthreads();
  if (tid < 128){
    float sum = 0.f;
    #pragma unroll
    for (int r = 0; r < 32; r++) sum += red[r][tid];
    s_e[e*128 + tid] = sum;
  }
}

// ---------------- tiny GEMM: m[e] = (s_e[e] * Be) @ W, packed bf16 out ----------------
__global__ __launch_bounds__(128) void egemm_kernel(
    const float* __restrict__ s_e, const int* __restrict__ eoff,
    const float* __restrict__ Wtf, uint32_t* __restrict__ mbf)
{
  __shared__ float srow[128];
  __shared__ float sacc[128];
  int e = blockIdx.x, n = threadIdx.x;
  srow[n] = s_e[e*128 + n];
  __syncthreads();
  int deg = eoff[e+1] - eoff[e];
  float be = deg > 0 ? 1.f/(float)deg : 0.f;
  const f32x4* w4 = (const f32x4*)(Wtf + n*128);
  float acc = 0.f;
  #pragma unroll
  for (int k = 0; k < 32; k++){
    f32x4 qv = w4[k];
    acc += qv[0]*srow[k*4] + qv[1]*srow[k*4+1] + qv[2]*srow[k*4+2] + qv[3]*srow[k*4+3];
  }
  sacc[n] = acc * be;
  __syncthreads();
  if (n < 64){
    uint32_t lo = f2bf(sacc[2*n]);
    uint32_t hi = f2bf(sacc[2*n+1]);
    mbf[e*64 + n] = (hi << 16) | lo;
  }
}

// ---------------- node gather: merged visit stream, wave-per-node-chunk ----------------
// Each wave owns nodes [v0,v1) and streams their visits [noff[v0], noff[v1)) as ONE
// continuous 4-deep-pipelined loop (prefetch crosses node boundaries -> no drain at
// avg-degree-8 nodes). Node boundaries are wave-uniform scalar compares; flush writes
// the finished node. nedges holds pre-scaled u32-row offsets (e<<6).
__global__ __launch_bounds__(256) void node_gather_kernel(
    const uint32_t* __restrict__ mbf, const int* __restrict__ noff,
    const int* __restrict__ nedges, const float* __restrict__ hb,
    uint32_t* __restrict__ outp)
{
  int wid  = (blockIdx.x << 2) | (threadIdx.x >> 6);
  int lane = threadIdx.x & 63;
  float b0 = hb[2*lane], b1 = hb[2*lane+1];
  const int K = (N_NODES + NG_WAVES - 1) / NG_WAVES;   // 25 nodes per wave
  int v0 = wid * K;
  int v1 = min(v0 + K, N_NODES);
  if (v0 >= v1) return;
  int s    = noff[v0];
  int send = noff[v1];

  int v   = v0;
  int vs  = s;                      // first visit of current node
  int bnd = noff[v0+1];             // end visit of current node
  float a0 = 0.f, a1 = 0.f;

  auto flush = [&](int iend){
    float dn = (iend > vs) ? 1.f/(float)(iend - vs) : 0.f;
    uint32_t lo = f2bf(a0*dn + b0);
    uint32_t hi = f2bf(a1*dn + b1);
    outp[((size_t)v << 6) | lane] = (hi << 16) | lo;
    a0 = 0.f; a1 = 0.f;
    vs = iend;
    v++;
    bnd = (v < v1) ? noff[v+1] : 0x7fffffff;
  };

  // 4-deep pipeline across the whole visit stream
  uint32_t r0 = (s     < send) ? mbf[nedges[s]     + lane] : 0u;
  uint32_t r1 = (s + 1 < send) ? mbf[nedges[s + 1] + lane] : 0u;
  uint32_t r2 = (s + 2 < send) ? mbf[nedges[s + 2] + lane] : 0u;
  uint32_t r3 = (s + 3 < send) ? mbf[nedges[s + 3] + lane] : 0u;

  for (int ii = s; ii < send; ii += 4){
    uint32_t q0 = (ii + 4 < send) ? mbf[nedges[ii + 4] + lane] : 0u;
    uint32_t q1 = (ii + 5 < send) ? mbf[nedges[ii + 5] + lane] : 0u;
    uint32_t q2 = (ii + 6 < send) ? mbf[nedges[ii + 6] + lane] : 0u;
    uint32_t q3 = (ii + 7 < send) ? mbf[nedges[ii + 7] + lane] : 0u;

    { while (bnd == ii) flush(ii);
      a0 += u2f(r0 << 16); a1 += u2f(r0 & 0xffff0000u); }
    if (ii + 1 < send){ while (bnd == ii + 1) flush(ii + 1);
      a0 += u2f(r1 << 16); a1 += u2f(r1 & 0xffff0000u); }
    if (ii + 2 < send){ while (bnd == ii + 2) flush(ii + 2);
      a0 += u2f(r2 << 16); a1 += u2f(r2 & 0xffff0000u); }
    if (ii + 3 < send){ while (bnd == ii + 3) flush(ii + 3);
      a0 += u2f(r3 << 16); a1 += u2f(r3 & 0xffff0000u); }

    r0 = q0; r1 = q1; r2 = q2; r3 = q3;
  }
  while (v < v1) flush(send);
}

// ---------------- host launch ----------------
extern "C" void kernel_launch(void* const* d_in, const int* in_sizes, int n_in,
                              void* d_out, int out_size, void* d_ws, size_t ws_size,
                              hipStream_t stream)
{
  (void)in_sizes; (void)n_in; (void)out_size; (void)ws_size;
  const float* x   = (const float*)d_in[0];
  const float* tbW = (const float*)d_in[1];
  const float* tbb = (const float*)d_in[2];
  const float* hgW = (const float*)d_in[3];
  const float* hgb = (const float*)d_in[4];
  const int* nidx  = (const int*)d_in[6];
  const int* eidx  = (const int*)d_in[7];
  float* out = (float*)d_out;

  char* p = (char*)d_ws;
  auto alloc = [&](size_t sz){ void* r = (void*)p; p += (sz + 255) & ~(size_t)255; return r; };
  unsigned short* hA = (unsigned short*)alloc((size_t)N_NODES*DIM*2);  // 51.2 MB
  unsigned short* hB = (unsigned short*)alloc((size_t)N_NODES*DIM*2);  // 51.2 MB
  unsigned char*  h8 = (unsigned char*)alloc((size_t)N_NODES*DIM);     // 25.6 MB
  float* s_e  = (float*)alloc((size_t)N_EDGES*DIM*4);                  // 512 KB
  uint32_t* mbf = (uint32_t*)alloc((size_t)N_EDGES*64*4);              // 256 KB (L2-resident)
  short* WtTb = (short*)alloc((size_t)5*384*128*2);
  float* Wtf  = (float*)alloc((size_t)2*128*128*4);
  int* ebh  = (int*)alloc((size_t)NBLK*N_EDGES*4);
  int* nbh  = (int*)alloc((size_t)NBLK*NCB*4);
  int* eoff = (int*)alloc((N_EDGES+1)*4);
  int* cbase= (int*)alloc((NCB+1)*4);
  int* noff = (int*)alloc((size_t)(N_NODES+1)*4);
  int* enodes = (int*)alloc((size_t)NNZ_C*4);
  int* nedges = (int*)alloc((size_t)NNZ_C*4);
  uint32_t* pairs = (uint32_t*)h8;   // transient: consumed by node_build before h8 is written

  prep_tb_w<<<960, 256, 0, stream>>>(tbW, WtTb);
  prep_hg_wf<<<128, 256, 0, stream>>>(hgW, Wtf);

  // CSR build (deterministic, no global atomics)
  hist_kernel<<<NBLK, 256, 0, stream>>>(nidx, eidx, ebh, nbh);
  escan_kernel<<<1, 1024, 0, stream>>>(ebh, eoff);
  nscan_kernel<<<1, 256, 0, stream>>>(nbh, cbase);
  scatter_kernel<<<NBLK, 256, 0, stream>>>(nidx, eidx, ebh, nbh, enodes, pairs);
  node_build_kernel<<<NCB, 256, 0, stream>>>(pairs, cbase, noff, nedges);

  // TB0: x (fp32) -> h8 (fp8)
  gemm_kernel<true, 2><<<1024, 256, 0, stream>>>(x, h8, WtTb, tbb);
  // conv0: gather-sum h8 -> s_e; m = (s_e*Be)@W0 (bf16-packed); node gather -> hA (bf16)
  edge_gather_kernel<<<N_EDGES, 256, 0, stream>>>(h8, eoff, enodes, s_e);
  egemm_kernel<<<N_EDGES, 128, 0, stream>>>(s_e, eoff, Wtf, mbf);
  node_gather_kernel<<<NG_BLOCKS, 256, 0, stream>>>(mbf, noff, nedges, hgb, (uint32_t*)hA);
  // TB1: hA -> hB (bf16), TB2: hB -> h8 (fp8)
  gemm_kernel<false, 0><<<1024, 256, 0, stream>>>(hA, hB, WtTb + 1*49152, tbb + 1*384);
  gemm_kernel<false, 2><<<1024, 256, 0, stream>>>(hB, h8, WtTb + 2*49152, tbb + 2*384);
  // conv1
  edge_gather_kernel<<<N_EDGES, 256, 0, stream>>>(h8, eoff, enodes, s_e);
  egemm_kernel<<<N_EDGES, 128, 0, stream>>>(s_e, eoff, Wtf + 16384, mbf);
  node_gather_kernel<<<NG_BLOCKS, 256, 0, stream>>>(mbf, noff, nedges, hgb + 128, (uint32_t*)hA);
  // TB3: hA -> hB, TB4: hB -> out (fp32)
  gemm_kernel<false, 0><<<1024, 256, 0, stream>>>(hA, hB, WtTb + 3*49152, tbb + 3*384);
  gemm_kernel<false, 1><<<1024, 256, 0, stream>>>(hB, out, WtTb + 4*49152, tbb + 4*384);
}

// Round 5
// 673.998 us; speedup vs baseline: 1.0605x; 1.0605x over previous
//
#include <hip/hip_runtime.h>
#include <stdint.h>

// ---------------- constants ----------------
#define N_NODES 200000
#define DIM     128
#define N_EDGES 1024
#define NNZ_C   1600000
#define NT_TILES 6250        // N_NODES / 32 exactly

// CSR-build binning
#define NBLK   250           // histogram/scatter blocks
#define CHUNK  6400          // NNZ / NBLK
#define ITERS  25            // CHUNK / 256
#define NCB    196           // coarse node buckets of 1024 nodes

// node_gather: wave-per-node-chunk direct-L2 gather, 2x oversubscribed
#define NG_BLOCKS 4096
#define NG_WAVES  (NG_BLOCKS*4)   // 16384 waves

typedef __attribute__((ext_vector_type(8))) short short8;   // 8 bf16 (4 VGPRs)
typedef __attribute__((ext_vector_type(4))) float f32x4;

__device__ __forceinline__ float u2f(uint32_t u){ union{uint32_t u;float f;} x; x.u=u; return x.f; }
__device__ __forceinline__ uint32_t f2u(float f){ union{uint32_t u;float f;} x; x.f=f; return x.u; }
__device__ __forceinline__ unsigned short f2bf(float f){
  uint32_t u = f2u(f);
  u += 0x7fffu + ((u >> 16) & 1u);      // RNE
  return (unsigned short)(u >> 16);
}

// ---------------- weight prep ----------------
__global__ void prep_tb_w(const float* __restrict__ W, short* __restrict__ Wt){
  int i = blockIdx.x*256 + threadIdx.x;
  if (i >= 5*384*128) return;
  int k   = i & 127;
  int col = (i >> 7) % 384;
  int s   = i / 49152;
  int j = col >> 7, n = col & 127;
  Wt[i] = (short)f2bf(W[((s*3 + j)*128 + k)*128 + n]);
}
// hgW fp32 transposed: Wtf[g][n][k] = W[g][k][n]
__global__ void prep_hg_wf(const float* __restrict__ W, float* __restrict__ Wtf){
  int i = blockIdx.x*256 + threadIdx.x;
  if (i >= 2*128*128) return;
  int k = i & 127;
  int n = (i >> 7) & 127;
  int g = i >> 14;
  Wtf[i] = W[(g*128 + k)*128 + n];
}

// ---------------- CSR build: deterministic binned counting sort ----------------
__global__ __launch_bounds__(256) void hist_kernel(
    const int* __restrict__ nidx, const int* __restrict__ eidx,
    int* __restrict__ ebh, int* __restrict__ nbh)
{
  __shared__ int eh[N_EDGES];
  __shared__ int nh[NCB];
  int tid = threadIdx.x, blk = blockIdx.x;
  #pragma unroll
  for (int l = tid; l < N_EDGES; l += 256) eh[l] = 0;
  for (int l = tid; l < NCB; l += 256) nh[l] = 0;
  __syncthreads();
  int base = blk*CHUNK;
  for (int it = 0; it < ITERS; it++){
    int i = base + it*256 + tid;
    atomicAdd(&eh[eidx[i]], 1);
    atomicAdd(&nh[nidx[i] >> 10], 1);
  }
  __syncthreads();
  for (int l = tid; l < N_EDGES; l += 256) ebh[blk*N_EDGES + l] = eh[l];
  for (int l = tid; l < NCB; l += 256) nbh[blk*NCB + l] = nh[l];
}

__global__ __launch_bounds__(1024) void escan_kernel(
    int* __restrict__ ebh, int* __restrict__ eoff)
{
  __shared__ int sc[1024];
  int e = threadIdx.x;
  int total = 0;
  #pragma unroll 10
  for (int b = 0; b < NBLK; b++){
    int idx = b*N_EDGES + e;
    int t = ebh[idx];
    ebh[idx] = total;
    total += t;
  }
  sc[e] = total; __syncthreads();
  for (int off=1; off<1024; off<<=1){
    int v = (e >= off) ? sc[e-off] : 0;
    __syncthreads();
    sc[e] += v;
    __syncthreads();
  }
  int base = sc[e] - total;   // exclusive
  eoff[e] = base;
  if (e == 1023) eoff[1024] = sc[1023];
  #pragma unroll 10
  for (int b = 0; b < NBLK; b++) ebh[b*N_EDGES + e] += base;
}

__global__ __launch_bounds__(256) void nscan_kernel(
    int* __restrict__ nbh, int* __restrict__ cbase)
{
  __shared__ int sc[256];
  int c = threadIdx.x;
  int total = 0;
  if (c < NCB){
    #pragma unroll 10
    for (int b = 0; b < NBLK; b++){
      int idx = b*NCB + c;
      int t = nbh[idx];
      nbh[idx] = total;
      total += t;
    }
  }
  sc[c] = (c < NCB) ? total : 0; __syncthreads();
  for (int off=1; off<256; off<<=1){
    int v = (c >= off) ? sc[c-off] : 0;
    __syncthreads();
    sc[c] += v;
    __syncthreads();
  }
  int base = sc[c] - ((c < NCB) ? total : 0);
  if (c < NCB) cbase[c] = base;
  if (c == NCB-1) cbase[NCB] = sc[c];
  __syncthreads();
  if (c < NCB){
    #pragma unroll 10
    for (int b = 0; b < NBLK; b++) nbh[b*NCB + c] += base;
  }
}

__global__ __launch_bounds__(256) void scatter_kernel(
    const int* __restrict__ nidx, const int* __restrict__ eidx,
    const int* __restrict__ ebh, const int* __restrict__ nbh,
    int* __restrict__ enodes, uint32_t* __restrict__ pairs)
{
  __shared__ int cure[N_EDGES];
  __shared__ int curn[NCB];
  int tid = threadIdx.x, blk = blockIdx.x;
  for (int l = tid; l < N_EDGES; l += 256) cure[l] = ebh[blk*N_EDGES + l];
  for (int l = tid; l < NCB; l += 256)     curn[l] = nbh[blk*NCB + l];
  __syncthreads();
  int base = blk*CHUNK;
  for (int it = 0; it < ITERS; it++){
    int i = base + it*256 + tid;
    int v = nidx[i], e = eidx[i];
    int pe = atomicAdd(&cure[e], 1);
    enodes[pe] = v;
    int pn = atomicAdd(&curn[v >> 10], 1);
    pairs[pn] = ((uint32_t)v << 10) | (uint32_t)e;
  }
}

__global__ __launch_bounds__(256) void node_build_kernel(
    const uint32_t* __restrict__ pairs, const int* __restrict__ cbase,
    int* __restrict__ noff, int* __restrict__ nedges)
{
  __shared__ int cnt[1024];
  __shared__ int off[1024];
  __shared__ int part[256];
  int tid = threadIdx.x, c = blockIdx.x;
  int n0 = c << 10;
  int nloc = min(1024, N_NODES - n0);
  int s = cbase[c], e = cbase[c+1];
  #pragma unroll
  for (int l = tid; l < 1024; l += 256) cnt[l] = 0;
  __syncthreads();
  for (int i = s + tid; i < e; i += 256)
    atomicAdd(&cnt[(pairs[i] >> 10) & 1023], 1);
  __syncthreads();
  int c0 = cnt[tid*4], c1 = cnt[tid*4+1], c2 = cnt[tid*4+2], c3 = cnt[tid*4+3];
  int sum = c0+c1+c2+c3;
  part[tid] = sum; __syncthreads();
  for (int o=1; o<256; o<<=1){
    int v = (tid >= o) ? part[tid-o] : 0;
    __syncthreads();
    part[tid] += v;
    __syncthreads();
  }
  int pb = part[tid] - sum;
  off[tid*4]   = pb;
  off[tid*4+1] = pb + c0;
  off[tid*4+2] = pb + c0 + c1;
  off[tid*4+3] = pb + c0 + c1 + c2;
  __syncthreads();
  for (int l = tid; l < nloc; l += 256) noff[n0 + l] = s + off[l];
  if (c == 0 && tid == 0) noff[N_NODES] = NNZ_C;
  __syncthreads();
  for (int i = s + tid; i < e; i += 256){
    uint32_t p = pairs[i];
    int local = (p >> 10) & 1023;
    int pos = s + atomicAdd(&off[local], 1);
    nedges[pos] = (int)((p & 1023) << 6);   // pre-scaled: float2-row offset of edge in mf
  }
}

// ---------------- GEMM: [N,128] @ [128, 3*128], MFMA 16x16x32 bf16 ----------------
// OUT_MODE: 0 = bf16, 1 = f32, 2 = fp8(e4m3)
template<bool IN_F32, int OUT_MODE>
__global__ __launch_bounds__(256, 2) void gemm_kernel(
    const void* __restrict__ in, void* __restrict__ out,
    const short* __restrict__ Wt, const float* __restrict__ bias)
{
  __shared__ short Atile[32][136];
  const int tid  = threadIdx.x;
  const int lane = tid & 63;
  const int w    = tid >> 6;
  const int l15  = lane & 15;
  const int quad = lane >> 4;

  short8 bfrag[3][2][4];
  #pragma unroll
  for (int j = 0; j < 3; j++)
    #pragma unroll
    for (int nt = 0; nt < 2; nt++){
      const short* bp = Wt + (j*128 + w*32 + nt*16 + l15)*128 + quad*8;
      #pragma unroll
      for (int ks = 0; ks < 4; ks++)
        bfrag[j][nt][ks] = *(const short8*)(bp + ks*32);
    }

  float bv[3][2];
  #pragma unroll
  for (int j = 0; j < 3; j++)
    #pragma unroll
    for (int nt = 0; nt < 2; nt++)
      bv[j][nt] = bias[j*128 + w*32 + nt*16 + l15];

  const int arow = tid >> 3;
  const int aseg = (tid & 7) * 2;

  short8 pre0, pre1;
  auto loadA = [&](int t){
    int off = (t*32 + arow)*128 + aseg*8;
    if (IN_F32){
      const float* f = (const float*)in + off;
      f32x4 q0 = ((const f32x4*)f)[0];
      f32x4 q1 = ((const f32x4*)f)[1];
      f32x4 q2 = ((const f32x4*)f)[2];
      f32x4 q3 = ((const f32x4*)f)[3];
      short8 t0, t1;
      #pragma unroll
      for (int u = 0; u < 4; u++){
        t0[u]   = (short)f2bf(q0[u]);
        t0[u+4] = (short)f2bf(q1[u]);
        t1[u]   = (short)f2bf(q2[u]);
        t1[u+4] = (short)f2bf(q3[u]);
      }
      pre0 = t0; pre1 = t1;
    } else {
      const short* hp = (const short*)in + off;
      pre0 = *(const short8*)hp;
      pre1 = *(const short8*)(hp + 8);
    }
  };

  int t = blockIdx.x;
  loadA(t);
  for (;;){
    __syncthreads();
    *(short8*)&Atile[arow][aseg*8]     = pre0;
    *(short8*)&Atile[arow][aseg*8 + 8] = pre1;
    __syncthreads();
    int tn = t + gridDim.x;
    if (tn < NT_TILES) loadA(tn);

    const int base = t*32;
    #pragma unroll
    for (int rt = 0; rt < 2; rt++){
      short8 af[4];
      #pragma unroll
      for (int ks = 0; ks < 4; ks++)
        af[ks] = *(const short8*)&Atile[rt*16 + l15][ks*32 + quad*8];

      f32x4 acc[3][2];
      #pragma unroll
      for (int j = 0; j < 3; j++)
        #pragma unroll
        for (int nt = 0; nt < 2; nt++){
          acc[j][nt] = (f32x4){0.f, 0.f, 0.f, 0.f};
          #pragma unroll
          for (int ks = 0; ks < 4; ks++)
            acc[j][nt] = __builtin_amdgcn_mfma_f32_16x16x32_bf16(
                af[ks], bfrag[j][nt][ks], acc[j][nt], 0, 0, 0);
        }

      #pragma unroll
      for (int nt = 0; nt < 2; nt++){
        int col = w*32 + nt*16 + l15;
        #pragma unroll
        for (int r = 0; r < 4; r++){
          int row = base + rt*16 + quad*4 + r;
          float c2 = acc[1][nt][r] + bv[1][nt];
          float sg = 1.f / (1.f + __expf(-c2));
          float v = acc[0][nt][r] + bv[0][nt] + sg + acc[2][nt][r] + bv[2][nt];
          v = fmaxf(v, 0.f);
          if (OUT_MODE == 1) ((float*)out)[row*128 + col] = v;
          else if (OUT_MODE == 0) ((unsigned short*)out)[row*128 + col] = f2bf(v);
          else {
            int pk = __builtin_amdgcn_cvt_pk_fp8_f32(v, v, 0, false);
            ((unsigned char*)out)[row*128 + col] = (unsigned char)(pk & 0xff);
          }
        }
      }
    }
    if (tn >= NT_TILES) break;
    t = tn;
  }
}

// ---------------- edge gather-sum of fp8 h: s_e[e] = sum_{v in e} h8[v] ----------------
// One block per edge; 8 lanes x 16 B per row, 32 row-slots; 4-deep pipeline.
__device__ __forceinline__ void acc16(float* a, uint4 r){
  uint32_t w[4] = {r.x, r.y, r.z, r.w};
  #pragma unroll
  for (int q = 0; q < 4; q++){
    auto lo = __builtin_amdgcn_cvt_pk_f32_fp8(w[q], false);
    auto hi = __builtin_amdgcn_cvt_pk_f32_fp8(w[q], true);
    a[q*4+0] += lo[0]; a[q*4+1] += lo[1]; a[q*4+2] += hi[0]; a[q*4+3] += hi[1];
  }
}

__global__ __launch_bounds__(256) void edge_gather_kernel(
    const unsigned char* __restrict__ h8, const int* __restrict__ eoff,
    const int* __restrict__ enodes, float* __restrict__ s_e)
{
  int e = blockIdx.x;
  int s = eoff[e], en = eoff[e+1];
  int tid  = threadIdx.x;
  int slot = tid >> 3;          // 32 row-slots
  int ch   = tid & 7;           // 16 B per lane
  const size_t choff = (size_t)ch * 16;

  float a[16];
  #pragma unroll
  for (int j = 0; j < 16; j++) a[j] = 0.f;

  int i0 = s + slot;
  int n0 = (i0      < en) ? enodes[i0]      : -1;
  int n1 = (i0 + 32 < en) ? enodes[i0 + 32] : -1;
  int n2 = (i0 + 64 < en) ? enodes[i0 + 64] : -1;
  int n3 = (i0 + 96 < en) ? enodes[i0 + 96] : -1;

  while (i0 < en){
    int i1 = i0 + 128;
    int m0 = (i1      < en) ? enodes[i1]      : -1;
    int m1 = (i1 + 32 < en) ? enodes[i1 + 32] : -1;
    int m2 = (i1 + 64 < en) ? enodes[i1 + 64] : -1;
    int m3 = (i1 + 96 < en) ? enodes[i1 + 96] : -1;

    uint4 r0 = *(const uint4*)(h8 + (((size_t)max(n0,0)) << 7) + choff);
    uint4 r1 = *(const uint4*)(h8 + (((size_t)max(n1,0)) << 7) + choff);
    uint4 r2 = *(const uint4*)(h8 + (((size_t)max(n2,0)) << 7) + choff);
    uint4 r3 = *(const uint4*)(h8 + (((size_t)max(n3,0)) << 7) + choff);
    if (n0 < 0) r0 = make_uint4(0,0,0,0);
    if (n1 < 0) r1 = make_uint4(0,0,0,0);
    if (n2 < 0) r2 = make_uint4(0,0,0,0);
    if (n3 < 0) r3 = make_uint4(0,0,0,0);

    acc16(a, r0); acc16(a, r1); acc16(a, r2); acc16(a, r3);

    n0 = m0; n1 = m1; n2 = m2; n3 = m3;
    i0 = i1;
  }

  __shared__ float red[32][132];
  #pragma unroll
  for (int j = 0; j < 16; j++) red[slot][ch*16 + j] = a[j];
  __syncthreads();
  if (tid < 128){
    float sum = 0.f;
    #pragma unroll
    for (int r = 0; r < 32; r++) sum += red[r][tid];
    s_e[e*128 + tid] = sum;
  }
}

// ---------------- tiny GEMM: mf[e] = (s_e[e] * Be) @ W, f32 out ----------------
__global__ __launch_bounds__(128) void egemm_kernel(
    const float* __restrict__ s_e, const int* __restrict__ eoff,
    const float* __restrict__ Wtf, float* __restrict__ mf)
{
  __shared__ float srow[128];
  int e = blockIdx.x, n = threadIdx.x;
  srow[n] = s_e[e*128 + n];
  __syncthreads();
  int deg = eoff[e+1] - eoff[e];
  float be = deg > 0 ? 1.f/(float)deg : 0.f;
  const f32x4* w4 = (const f32x4*)(Wtf + n*128);
  float acc = 0.f;
  #pragma unroll
  for (int k = 0; k < 32; k++){
    f32x4 qv = w4[k];
    acc += qv[0]*srow[k*4] + qv[1]*srow[k*4+1] + qv[2]*srow[k*4+2] + qv[3]*srow[k*4+3];
  }
  mf[e*128 + n] = acc * be;
}

// ---------------- node gather: wave-per-node-chunk, index-prefetched pipeline ----------------
// Per node: 4-wide visit chunks with the NEXT chunk's indices loaded (clamped,
// branchless) before consuming the current chunk's rows -> one L2 round-trip per
// chunk instead of two. mf rows are f32 (L2-resident); lane loads its channel
// pair as one float2 (no bf16 unpack). Loop bounds via readfirstlane -> SALU.
__global__ __launch_bounds__(256) void node_gather_kernel(
    const float* __restrict__ mf, const int* __restrict__ noff,
    const int* __restrict__ nedges, const float* __restrict__ hb,
    uint32_t* __restrict__ outp)
{
  int wid  = (blockIdx.x << 2) | (threadIdx.x >> 6);
  int lane = threadIdx.x & 63;
  const float2* mfp = (const float2*)mf + lane;   // lane's channel pair; row stride 64 float2
  float b0 = hb[2*lane], b1 = hb[2*lane+1];
  const int K = (N_NODES + NG_WAVES - 1) / NG_WAVES;   // 13 nodes per wave
  int v0 = wid * K;
  int v1 = min(v0 + K, N_NODES);
  if (v0 >= v1) return;

  int s = __builtin_amdgcn_readfirstlane(noff[v0]);
  for (int v = v0; v < v1; v++){
    int e = __builtin_amdgcn_readfirstlane(noff[v+1]);
    float a0 = 0.f, a1 = 0.f, a2 = 0.f, a3 = 0.f;
    int i = s;
    int em4 = e - 4;
    if (i <= em4){
      int e0 = nedges[i], e1 = nedges[i+1], e2 = nedges[i+2], e3 = nedges[i+3];
      for (; i <= em4; i += 4){
        int j = min(i + 4, em4);     // clamped next-chunk base (discarded past end)
        int p0 = nedges[j], p1 = nedges[j+1], p2 = nedges[j+2], p3 = nedges[j+3];
        float2 r0 = mfp[e0];
        float2 r1 = mfp[e1];
        float2 r2 = mfp[e2];
        float2 r3 = mfp[e3];
        a0 += r0.x; a1 += r0.y; a2 += r1.x; a3 += r1.y;
        a0 += r2.x; a1 += r2.y; a2 += r3.x; a3 += r3.y;
        e0 = p0; e1 = p1; e2 = p2; e3 = p3;
      }
    }
    for (; i < e; i++){
      float2 r = mfp[nedges[i]];
      a0 += r.x; a1 += r.y;
    }
    a0 += a2; a1 += a3;
    float dn = (e > s) ? 1.f/(float)(e - s) : 0.f;
    uint32_t lo = f2bf(a0*dn + b0);
    uint32_t hi = f2bf(a1*dn + b1);
    outp[((size_t)v << 6) | lane] = (hi << 16) | lo;
    s = e;
  }
}

// ---------------- host launch ----------------
extern "C" void kernel_launch(void* const* d_in, const int* in_sizes, int n_in,
                              void* d_out, int out_size, void* d_ws, size_t ws_size,
                              hipStream_t stream)
{
  (void)in_sizes; (void)n_in; (void)out_size; (void)ws_size;
  const float* x   = (const float*)d_in[0];
  const float* tbW = (const float*)d_in[1];
  const float* tbb = (const float*)d_in[2];
  const float* hgW = (const float*)d_in[3];
  const float* hgb = (const float*)d_in[4];
  const int* nidx  = (const int*)d_in[6];
  const int* eidx  = (const int*)d_in[7];
  float* out = (float*)d_out;

  char* p = (char*)d_ws;
  auto alloc = [&](size_t sz){ void* r = (void*)p; p += (sz + 255) & ~(size_t)255; return r; };
  unsigned short* hA = (unsigned short*)alloc((size_t)N_NODES*DIM*2);  // 51.2 MB
  unsigned short* hB = (unsigned short*)alloc((size_t)N_NODES*DIM*2);  // 51.2 MB
  unsigned char*  h8 = (unsigned char*)alloc((size_t)N_NODES*DIM);     // 25.6 MB
  float* s_e  = (float*)alloc((size_t)N_EDGES*DIM*4);                  // 512 KB
  float* mf   = (float*)alloc((size_t)N_EDGES*DIM*4);                  // 512 KB (L2-resident)
  short* WtTb = (short*)alloc((size_t)5*384*128*2);
  float* Wtf  = (float*)alloc((size_t)2*128*128*4);
  int* ebh  = (int*)alloc((size_t)NBLK*N_EDGES*4);
  int* nbh  = (int*)alloc((size_t)NBLK*NCB*4);
  int* eoff = (int*)alloc((N_EDGES+1)*4);
  int* cbase= (int*)alloc((NCB+1)*4);
  int* noff = (int*)alloc((size_t)(N_NODES+1)*4);
  int* enodes = (int*)alloc((size_t)NNZ_C*4);
  int* nedges = (int*)alloc((size_t)NNZ_C*4);
  uint32_t* pairs = (uint32_t*)h8;   // transient: consumed by node_build before h8 is written

  prep_tb_w<<<960, 256, 0, stream>>>(tbW, WtTb);
  prep_hg_wf<<<128, 256, 0, stream>>>(hgW, Wtf);

  // CSR build (deterministic, no global atomics)
  hist_kernel<<<NBLK, 256, 0, stream>>>(nidx, eidx, ebh, nbh);
  escan_kernel<<<1, 1024, 0, stream>>>(ebh, eoff);
  nscan_kernel<<<1, 256, 0, stream>>>(nbh, cbase);
  scatter_kernel<<<NBLK, 256, 0, stream>>>(nidx, eidx, ebh, nbh, enodes, pairs);
  node_build_kernel<<<NCB, 256, 0, stream>>>(pairs, cbase, noff, nedges);

  // TB0: x (fp32) -> h8 (fp8)
  gemm_kernel<true, 2><<<1024, 256, 0, stream>>>(x, h8, WtTb, tbb);
  // conv0: gather-sum h8 -> s_e; mf = (s_e*Be)@W0 (f32); node gather -> hA (bf16)
  edge_gather_kernel<<<N_EDGES, 256, 0, stream>>>(h8, eoff, enodes, s_e);
  egemm_kernel<<<N_EDGES, 128, 0, stream>>>(s_e, eoff, Wtf, mf);
  node_gather_kernel<<<NG_BLOCKS, 256, 0, stream>>>(mf, noff, nedges, hgb, (uint32_t*)hA);
  // TB1: hA -> hB (bf16), TB2: hB -> h8 (fp8)
  gemm_kernel<false, 0><<<1024, 256, 0, stream>>>(hA, hB, WtTb + 1*49152, tbb + 1*384);
  gemm_kernel<false, 2><<<1024, 256, 0, stream>>>(hB, h8, WtTb + 2*49152, tbb + 2*384);
  // conv1
  edge_gather_kernel<<<N_EDGES, 256, 0, stream>>>(h8, eoff, enodes, s_e);
  egemm_kernel<<<N_EDGES, 128, 0, stream>>>(s_e, eoff, Wtf + 16384, mf);
  node_gather_kernel<<<NG_BLOCKS, 256, 0, stream>>>(mf, noff, nedges, hgb + 128, (uint32_t*)hA);
  // TB3: hA -> hB, TB4: hB -> out (fp32)
  gemm_kernel<false, 0><<<1024, 256, 0, stream>>>(hA, hB, WtTb + 3*49152, tbb + 3*384);
  gemm_kernel<false, 1><<<1024, 256, 0, stream>>>(hB, out, WtTb + 4*49152, tbb + 4*384);
}

// Round 6
// 655.532 us; speedup vs baseline: 1.0904x; 1.0282x over previous
//
#include <hip/hip_runtime.h>
#include <stdint.h>

// ---------------- constants ----------------
#define N_NODES 200000
#define DIM     128
#define N_EDGES 1024
#define NNZ_C   1600000
#define NT_TILES 6250        // N_NODES / 32 exactly

// CSR-build binning
#define NBLK   250           // histogram/scatter blocks
#define CHUNK  6400          // NNZ / NBLK
#define ITERS  25            // CHUNK / 256
#define NCB    196           // coarse node buckets of 1024 nodes

// node_gather: LDS-staged indices, 8-deep row pipeline
#define NG_BLOCKS 2000
#define NG_WAVES  (NG_BLOCKS*4)   // 8000 waves
#define NG_K      25              // nodes per wave: 8000*25 = 200000 exactly
#define NG_STAGE  512             // staged visits per wave (P(exceed) ~ 0; guarded)

typedef __attribute__((ext_vector_type(8))) short short8;   // 8 bf16 (4 VGPRs)
typedef __attribute__((ext_vector_type(4))) float f32x4;

__device__ __forceinline__ float u2f(uint32_t u){ union{uint32_t u;float f;} x; x.u=u; return x.f; }
__device__ __forceinline__ uint32_t f2u(float f){ union{uint32_t u;float f;} x; x.f=f; return x.u; }
__device__ __forceinline__ unsigned short f2bf(float f){
  uint32_t u = f2u(f);
  u += 0x7fffu + ((u >> 16) & 1u);      // RNE
  return (unsigned short)(u >> 16);
}

// ---------------- weight prep ----------------
__global__ void prep_tb_w(const float* __restrict__ W, short* __restrict__ Wt){
  int i = blockIdx.x*256 + threadIdx.x;
  if (i >= 5*384*128) return;
  int k   = i & 127;
  int col = (i >> 7) % 384;
  int s   = i / 49152;
  int j = col >> 7, n = col & 127;
  Wt[i] = (short)f2bf(W[((s*3 + j)*128 + k)*128 + n]);
}
// hgW fp32 transposed: Wtf[g][n][k] = W[g][k][n]
__global__ void prep_hg_wf(const float* __restrict__ W, float* __restrict__ Wtf){
  int i = blockIdx.x*256 + threadIdx.x;
  if (i >= 2*128*128) return;
  int k = i & 127;
  int n = (i >> 7) & 127;
  int g = i >> 14;
  Wtf[i] = W[(g*128 + k)*128 + n];
}

// ---------------- CSR build: deterministic binned counting sort ----------------
__global__ __launch_bounds__(256) void hist_kernel(
    const int* __restrict__ nidx, const int* __restrict__ eidx,
    int* __restrict__ ebh, int* __restrict__ nbh)
{
  __shared__ int eh[N_EDGES];
  __shared__ int nh[NCB];
  int tid = threadIdx.x, blk = blockIdx.x;
  #pragma unroll
  for (int l = tid; l < N_EDGES; l += 256) eh[l] = 0;
  for (int l = tid; l < NCB; l += 256) nh[l] = 0;
  __syncthreads();
  int base = blk*CHUNK;
  for (int it = 0; it < ITERS; it++){
    int i = base + it*256 + tid;
    atomicAdd(&eh[eidx[i]], 1);
    atomicAdd(&nh[nidx[i] >> 10], 1);
  }
  __syncthreads();
  for (int l = tid; l < N_EDGES; l += 256) ebh[blk*N_EDGES + l] = eh[l];
  for (int l = tid; l < NCB; l += 256) nbh[blk*NCB + l] = nh[l];
}

__global__ __launch_bounds__(1024) void escan_kernel(
    int* __restrict__ ebh, int* __restrict__ eoff)
{
  __shared__ int sc[1024];
  int e = threadIdx.x;
  int total = 0;
  #pragma unroll 10
  for (int b = 0; b < NBLK; b++){
    int idx = b*N_EDGES + e;
    int t = ebh[idx];
    ebh[idx] = total;
    total += t;
  }
  sc[e] = total; __syncthreads();
  for (int off=1; off<1024; off<<=1){
    int v = (e >= off) ? sc[e-off] : 0;
    __syncthreads();
    sc[e] += v;
    __syncthreads();
  }
  int base = sc[e] - total;   // exclusive
  eoff[e] = base;
  if (e == 1023) eoff[1024] = sc[1023];
  #pragma unroll 10
  for (int b = 0; b < NBLK; b++) ebh[b*N_EDGES + e] += base;
}

__global__ __launch_bounds__(256) void nscan_kernel(
    int* __restrict__ nbh, int* __restrict__ cbase)
{
  __shared__ int sc[256];
  int c = threadIdx.x;
  int total = 0;
  if (c < NCB){
    #pragma unroll 10
    for (int b = 0; b < NBLK; b++){
      int idx = b*NCB + c;
      int t = nbh[idx];
      nbh[idx] = total;
      total += t;
    }
  }
  sc[c] = (c < NCB) ? total : 0; __syncthreads();
  for (int off=1; off<256; off<<=1){
    int v = (c >= off) ? sc[c-off] : 0;
    __syncthreads();
    sc[c] += v;
    __syncthreads();
  }
  int base = sc[c] - ((c < NCB) ? total : 0);
  if (c < NCB) cbase[c] = base;
  if (c == NCB-1) cbase[NCB] = sc[c];
  __syncthreads();
  if (c < NCB){
    #pragma unroll 10
    for (int b = 0; b < NBLK; b++) nbh[b*NCB + c] += base;
  }
}

__global__ __launch_bounds__(256) void scatter_kernel(
    const int* __restrict__ nidx, const int* __restrict__ eidx,
    const int* __restrict__ ebh, const int* __restrict__ nbh,
    int* __restrict__ enodes, uint32_t* __restrict__ pairs)
{
  __shared__ int cure[N_EDGES];
  __shared__ int curn[NCB];
  int tid = threadIdx.x, blk = blockIdx.x;
  for (int l = tid; l < N_EDGES; l += 256) cure[l] = ebh[blk*N_EDGES + l];
  for (int l = tid; l < NCB; l += 256)     curn[l] = nbh[blk*NCB + l];
  __syncthreads();
  int base = blk*CHUNK;
  for (int it = 0; it < ITERS; it++){
    int i = base + it*256 + tid;
    int v = nidx[i], e = eidx[i];
    int pe = atomicAdd(&cure[e], 1);
    enodes[pe] = v;
    int pn = atomicAdd(&curn[v >> 10], 1);
    pairs[pn] = ((uint32_t)v << 10) | (uint32_t)e;
  }
}

__global__ __launch_bounds__(256) void node_build_kernel(
    const uint32_t* __restrict__ pairs, const int* __restrict__ cbase,
    int* __restrict__ noff, int* __restrict__ nedges)
{
  __shared__ int cnt[1024];
  __shared__ int off[1024];
  __shared__ int part[256];
  int tid = threadIdx.x, c = blockIdx.x;
  int n0 = c << 10;
  int nloc = min(1024, N_NODES - n0);
  int s = cbase[c], e = cbase[c+1];
  #pragma unroll
  for (int l = tid; l < 1024; l += 256) cnt[l] = 0;
  __syncthreads();
  for (int i = s + tid; i < e; i += 256)
    atomicAdd(&cnt[(pairs[i] >> 10) & 1023], 1);
  __syncthreads();
  int c0 = cnt[tid*4], c1 = cnt[tid*4+1], c2 = cnt[tid*4+2], c3 = cnt[tid*4+3];
  int sum = c0+c1+c2+c3;
  part[tid] = sum; __syncthreads();
  for (int o=1; o<256; o<<=1){
    int v = (tid >= o) ? part[tid-o] : 0;
    __syncthreads();
    part[tid] += v;
    __syncthreads();
  }
  int pb = part[tid] - sum;
  off[tid*4]   = pb;
  off[tid*4+1] = pb + c0;
  off[tid*4+2] = pb + c0 + c1;
  off[tid*4+3] = pb + c0 + c1 + c2;
  __syncthreads();
  for (int l = tid; l < nloc; l += 256) noff[n0 + l] = s + off[l];
  if (c == 0 && tid == 0) noff[N_NODES] = NNZ_C;
  __syncthreads();
  for (int i = s + tid; i < e; i += 256){
    uint32_t p = pairs[i];
    int local = (p >> 10) & 1023;
    int pos = s + atomicAdd(&off[local], 1);
    nedges[pos] = (int)((p & 1023) << 8);   // BYTE offset of edge row in mbf (256 B rows)
  }
}

// ---------------- GEMM: [N,128] @ [128, 3*128], MFMA 16x16x32 bf16 ----------------
// OUT_MODE: 0 = bf16, 1 = f32, 2 = fp8(e4m3)
template<bool IN_F32, int OUT_MODE>
__global__ __launch_bounds__(256, 2) void gemm_kernel(
    const void* __restrict__ in, void* __restrict__ out,
    const short* __restrict__ Wt, const float* __restrict__ bias)
{
  __shared__ short Atile[32][136];
  const int tid  = threadIdx.x;
  const int lane = tid & 63;
  const int w    = tid >> 6;
  const int l15  = lane & 15;
  const int quad = lane >> 4;

  short8 bfrag[3][2][4];
  #pragma unroll
  for (int j = 0; j < 3; j++)
    #pragma unroll
    for (int nt = 0; nt < 2; nt++){
      const short* bp = Wt + (j*128 + w*32 + nt*16 + l15)*128 + quad*8;
      #pragma unroll
      for (int ks = 0; ks < 4; ks++)
        bfrag[j][nt][ks] = *(const short8*)(bp + ks*32);
    }

  float bv[3][2];
  #pragma unroll
  for (int j = 0; j < 3; j++)
    #pragma unroll
    for (int nt = 0; nt < 2; nt++)
      bv[j][nt] = bias[j*128 + w*32 + nt*16 + l15];

  const int arow = tid >> 3;
  const int aseg = (tid & 7) * 2;

  short8 pre0, pre1;
  auto loadA = [&](int t){
    int off = (t*32 + arow)*128 + aseg*8;
    if (IN_F32){
      const float* f = (const float*)in + off;
      f32x4 q0 = ((const f32x4*)f)[0];
      f32x4 q1 = ((const f32x4*)f)[1];
      f32x4 q2 = ((const f32x4*)f)[2];
      f32x4 q3 = ((const f32x4*)f)[3];
      short8 t0, t1;
      #pragma unroll
      for (int u = 0; u < 4; u++){
        t0[u]   = (short)f2bf(q0[u]);
        t0[u+4] = (short)f2bf(q1[u]);
        t1[u]   = (short)f2bf(q2[u]);
        t1[u+4] = (short)f2bf(q3[u]);
      }
      pre0 = t0; pre1 = t1;
    } else {
      const short* hp = (const short*)in + off;
      pre0 = *(const short8*)hp;
      pre1 = *(const short8*)(hp + 8);
    }
  };

  int t = blockIdx.x;
  loadA(t);
  for (;;){
    __syncthreads();
    *(short8*)&Atile[arow][aseg*8]     = pre0;
    *(short8*)&Atile[arow][aseg*8 + 8] = pre1;
    __syncthreads();
    int tn = t + gridDim.x;
    if (tn < NT_TILES) loadA(tn);

    const int base = t*32;
    #pragma unroll
    for (int rt = 0; rt < 2; rt++){
      short8 af[4];
      #pragma unroll
      for (int ks = 0; ks < 4; ks++)
        af[ks] = *(const short8*)&Atile[rt*16 + l15][ks*32 + quad*8];

      f32x4 acc[3][2];
      #pragma unroll
      for (int j = 0; j < 3; j++)
        #pragma unroll
        for (int nt = 0; nt < 2; nt++){
          acc[j][nt] = (f32x4){0.f, 0.f, 0.f, 0.f};
          #pragma unroll
          for (int ks = 0; ks < 4; ks++)
            acc[j][nt] = __builtin_amdgcn_mfma_f32_16x16x32_bf16(
                af[ks], bfrag[j][nt][ks], acc[j][nt], 0, 0, 0);
        }

      #pragma unroll
      for (int nt = 0; nt < 2; nt++){
        int col = w*32 + nt*16 + l15;
        #pragma unroll
        for (int r = 0; r < 4; r++){
          int row = base + rt*16 + quad*4 + r;
          float c2 = acc[1][nt][r] + bv[1][nt];
          float sg = 1.f / (1.f + __expf(-c2));
          float v = acc[0][nt][r] + bv[0][nt] + sg + acc[2][nt][r] + bv[2][nt];
          v = fmaxf(v, 0.f);
          if (OUT_MODE == 1) ((float*)out)[row*128 + col] = v;
          else if (OUT_MODE == 0) ((unsigned short*)out)[row*128 + col] = f2bf(v);
          else {
            int pk = __builtin_amdgcn_cvt_pk_fp8_f32(v, v, 0, false);
            ((unsigned char*)out)[row*128 + col] = (unsigned char)(pk & 0xff);
          }
        }
      }
    }
    if (tn >= NT_TILES) break;
    t = tn;
  }
}

// ---------------- edge gather-sum of fp8 h: s_e[e] = sum_{v in e} h8[v] ----------------
// One block per edge; 8 lanes x 16 B per row, 32 row-slots; 4-deep pipeline.
__device__ __forceinline__ void acc16(float* a, uint4 r){
  uint32_t w[4] = {r.x, r.y, r.z, r.w};
  #pragma unroll
  for (int q = 0; q < 4; q++){
    auto lo = __builtin_amdgcn_cvt_pk_f32_fp8(w[q], false);
    auto hi = __builtin_amdgcn_cvt_pk_f32_fp8(w[q], true);
    a[q*4+0] += lo[0]; a[q*4+1] += lo[1]; a[q*4+2] += hi[0]; a[q*4+3] += hi[1];
  }
}

__global__ __launch_bounds__(256) void edge_gather_kernel(
    const unsigned char* __restrict__ h8, const int* __restrict__ eoff,
    const int* __restrict__ enodes, float* __restrict__ s_e)
{
  int e = blockIdx.x;
  int s = eoff[e], en = eoff[e+1];
  int tid  = threadIdx.x;
  int slot = tid >> 3;          // 32 row-slots
  int ch   = tid & 7;           // 16 B per lane
  const size_t choff = (size_t)ch * 16;

  float a[16];
  #pragma unroll
  for (int j = 0; j < 16; j++) a[j] = 0.f;

  int i0 = s + slot;
  int n0 = (i0      < en) ? enodes[i0]      : -1;
  int n1 = (i0 + 32 < en) ? enodes[i0 + 32] : -1;
  int n2 = (i0 + 64 < en) ? enodes[i0 + 64] : -1;
  int n3 = (i0 + 96 < en) ? enodes[i0 + 96] : -1;

  while (i0 < en){
    int i1 = i0 + 128;
    int m0 = (i1      < en) ? enodes[i1]      : -1;
    int m1 = (i1 + 32 < en) ? enodes[i1 + 32] : -1;
    int m2 = (i1 + 64 < en) ? enodes[i1 + 64] : -1;
    int m3 = (i1 + 96 < en) ? enodes[i1 + 96] : -1;

    uint4 r0 = *(const uint4*)(h8 + (((size_t)max(n0,0)) << 7) + choff);
    uint4 r1 = *(const uint4*)(h8 + (((size_t)max(n1,0)) << 7) + choff);
    uint4 r2 = *(const uint4*)(h8 + (((size_t)max(n2,0)) << 7) + choff);
    uint4 r3 = *(const uint4*)(h8 + (((size_t)max(n3,0)) << 7) + choff);
    if (n0 < 0) r0 = make_uint4(0,0,0,0);
    if (n1 < 0) r1 = make_uint4(0,0,0,0);
    if (n2 < 0) r2 = make_uint4(0,0,0,0);
    if (n3 < 0) r3 = make_uint4(0,0,0,0);

    acc16(a, r0); acc16(a, r1); acc16(a, r2); acc16(a, r3);

    n0 = m0; n1 = m1; n2 = m2; n3 = m3;
    i0 = i1;
  }

  __shared__ float red[32][132];
  #pragma unroll
  for (int j = 0; j < 16; j++) red[slot][ch*16 + j] = a[j];
  __syncthreads();
  if (tid < 128){
    float sum = 0.f;
    #pragma unroll
    for (int r = 0; r < 32; r++) sum += red[r][tid];
    s_e[e*128 + tid] = sum;
  }
}

// ---------------- tiny GEMM: m[e] = (s_e[e] * Be) @ W, packed bf16 out ----------------
__global__ __launch_bounds__(128) void egemm_kernel(
    const float* __restrict__ s_e, const int* __restrict__ eoff,
    const float* __restrict__ Wtf, uint32_t* __restrict__ mbf)
{
  __shared__ float srow[128];
  __shared__ float sacc[128];
  int e = blockIdx.x, n = threadIdx.x;
  srow[n] = s_e[e*128 + n];
  __syncthreads();
  int deg = eoff[e+1] - eoff[e];
  float be = deg > 0 ? 1.f/(float)deg : 0.f;
  const f32x4* w4 = (const f32x4*)(Wtf + n*128);
  float acc = 0.f;
  #pragma unroll
  for (int k = 0; k < 32; k++){
    f32x4 qv = w4[k];
    acc += qv[0]*srow[k*4] + qv[1]*srow[k*4+1] + qv[2]*srow[k*4+2] + qv[3]*srow[k*4+3];
  }
  sacc[n] = acc * be;
  __syncthreads();
  if (n < 64){
    uint32_t lo = f2bf(sacc[2*n]);
    uint32_t hi = f2bf(sacc[2*n+1]);
    mbf[e*64 + n] = (hi << 16) | lo;
  }
}

// ---------------- node gather: LDS-staged indices + 8-deep row pipeline ----------------
// Wave owns 25 consecutive nodes. (1) Stage the wave's whole nedges segment
// (avg ~200, <=512 ints) into LDS with coalesced loads -> index reads leave the
// latency chain. (2) Per node, issue 8 row loads back-to-back with scalar-clamped
// LDS indices (dead slots reload row[e-1] -> L1 hit) and correct the overcount
// with one subtract. noff per node comes from a staged register via readlane.
__global__ __launch_bounds__(256) void node_gather_kernel(
    const uint32_t* __restrict__ mbf, const int* __restrict__ noff,
    const int* __restrict__ nedges, const float* __restrict__ hb,
    uint32_t* __restrict__ outp)
{
  __shared__ int sidx[4][NG_STAGE];
  const int wslot = threadIdx.x >> 6;
  const int wid   = (blockIdx.x << 2) | wslot;
  const int lane  = threadIdx.x & 63;
  const int lane4 = lane << 2;
  const float b0 = hb[2*lane], b1 = hb[2*lane+1];
  const int v0 = wid * NG_K;

  // staged per-node end offsets: lane l holds noff[v0+1+l]
  int eArr = noff[min(v0 + 1 + lane, N_NODES)];
  int sW   = __builtin_amdgcn_readfirstlane(noff[v0]);
  int send = __builtin_amdgcn_readlane(eArr, NG_K - 1);
  int n = send - sW;

  int* myIdx = sidx[wslot];
  bool useLds = (n <= NG_STAGE);
  if (useLds){
    for (int b = lane; b < n; b += 64) myIdx[b] = nedges[sW + b];
  }
  __syncthreads();

  const char* mb = (const char*)mbf;
  if (useLds){
    int s = sW;
    for (int vr = 0; vr < NG_K; vr++){
      int e = __builtin_amdgcn_readlane(eArr, vr);
      float a0 = 0.f, a1 = 0.f;
      uint32_t rlast = 0;
      for (int i = s; i < e; i += 8){
        uint32_t r[8];
        #pragma unroll
        for (int k = 0; k < 8; k++){
          int li = min(i + k, e - 1) - sW;
          r[k] = *(const uint32_t*)(mb + (myIdx[li] + lane4));
        }
        #pragma unroll
        for (int k = 0; k < 8; k++){
          a0 += u2f(r[k] << 16);
          a1 += u2f(r[k] & 0xffff0000u);
        }
        rlast = r[7];
      }
      int d = e - s;
      float dead = (float)(((d + 7) & ~7) - d);
      a0 -= dead * u2f(rlast << 16);
      a1 -= dead * u2f(rlast & 0xffff0000u);
      float dn = (d > 0) ? 1.f/(float)d : 0.f;
      uint32_t lo = f2bf(a0*dn + b0);
      uint32_t hi = f2bf(a1*dn + b1);
      outp[((size_t)(v0 + vr) << 6) | lane] = (hi << 16) | lo;
      s = e;
    }
  } else {
    // fallback (statistically never): direct global-index path
    int s = sW;
    for (int vr = 0; vr < NG_K; vr++){
      int e = __builtin_amdgcn_readlane(eArr, vr);
      float a0 = 0.f, a1 = 0.f;
      for (int i = s; i < e; i++){
        uint32_t r = *(const uint32_t*)(mb + (nedges[i] + lane4));
        a0 += u2f(r << 16);
        a1 += u2f(r & 0xffff0000u);
      }
      int d = e - s;
      float dn = (d > 0) ? 1.f/(float)d : 0.f;
      uint32_t lo = f2bf(a0*dn + b0);
      uint32_t hi = f2bf(a1*dn + b1);
      outp[((size_t)(v0 + vr) << 6) | lane] = (hi << 16) | lo;
      s = e;
    }
  }
}

// ---------------- host launch ----------------
extern "C" void kernel_launch(void* const* d_in, const int* in_sizes, int n_in,
                              void* d_out, int out_size, void* d_ws, size_t ws_size,
                              hipStream_t stream)
{
  (void)in_sizes; (void)n_in; (void)out_size; (void)ws_size;
  const float* x   = (const float*)d_in[0];
  const float* tbW = (const float*)d_in[1];
  const float* tbb = (const float*)d_in[2];
  const float* hgW = (const float*)d_in[3];
  const float* hgb = (const float*)d_in[4];
  const int* nidx  = (const int*)d_in[6];
  const int* eidx  = (const int*)d_in[7];
  float* out = (float*)d_out;

  char* p = (char*)d_ws;
  auto alloc = [&](size_t sz){ void* r = (void*)p; p += (sz + 255) & ~(size_t)255; return r; };
  unsigned short* hA = (unsigned short*)alloc((size_t)N_NODES*DIM*2);  // 51.2 MB
  unsigned short* hB = (unsigned short*)alloc((size_t)N_NODES*DIM*2);  // 51.2 MB
  unsigned char*  h8 = (unsigned char*)alloc((size_t)N_NODES*DIM);     // 25.6 MB
  float* s_e  = (float*)alloc((size_t)N_EDGES*DIM*4);                  // 512 KB
  uint32_t* mbf = (uint32_t*)alloc((size_t)N_EDGES*64*4);              // 256 KB (L2-resident)
  short* WtTb = (short*)alloc((size_t)5*384*128*2);
  float* Wtf  = (float*)alloc((size_t)2*128*128*4);
  int* ebh  = (int*)alloc((size_t)NBLK*N_EDGES*4);
  int* nbh  = (int*)alloc((size_t)NBLK*NCB*4);
  int* eoff = (int*)alloc((N_EDGES+1)*4);
  int* cbase= (int*)alloc((NCB+1)*4);
  int* noff = (int*)alloc((size_t)(N_NODES+1)*4);
  int* enodes = (int*)alloc((size_t)NNZ_C*4);
  int* nedges = (int*)alloc((size_t)NNZ_C*4 + 64);   // +pad
  uint32_t* pairs = (uint32_t*)h8;   // transient: consumed by node_build before h8 is written

  prep_tb_w<<<960, 256, 0, stream>>>(tbW, WtTb);
  prep_hg_wf<<<128, 256, 0, stream>>>(hgW, Wtf);

  // CSR build (deterministic, no global atomics)
  hist_kernel<<<NBLK, 256, 0, stream>>>(nidx, eidx, ebh, nbh);
  escan_kernel<<<1, 1024, 0, stream>>>(ebh, eoff);
  nscan_kernel<<<1, 256, 0, stream>>>(nbh, cbase);
  scatter_kernel<<<NBLK, 256, 0, stream>>>(nidx, eidx, ebh, nbh, enodes, pairs);
  node_build_kernel<<<NCB, 256, 0, stream>>>(pairs, cbase, noff, nedges);

  // TB0: x (fp32) -> h8 (fp8)
  gemm_kernel<true, 2><<<1024, 256, 0, stream>>>(x, h8, WtTb, tbb);
  // conv0: gather-sum h8 -> s_e; m = (s_e*Be)@W0 (bf16-packed); node gather -> hA (bf16)
  edge_gather_kernel<<<N_EDGES, 256, 0, stream>>>(h8, eoff, enodes, s_e);
  egemm_kernel<<<N_EDGES, 128, 0, stream>>>(s_e, eoff, Wtf, mbf);
  node_gather_kernel<<<NG_BLOCKS, 256, 0, stream>>>(mbf, noff, nedges, hgb, (uint32_t*)hA);
  // TB1: hA -> hB (bf16), TB2: hB -> h8 (fp8)
  gemm_kernel<false, 0><<<1024, 256, 0, stream>>>(hA, hB, WtTb + 1*49152, tbb + 1*384);
  gemm_kernel<false, 2><<<1024, 256, 0, stream>>>(hB, h8, WtTb + 2*49152, tbb + 2*384);
  // conv1
  edge_gather_kernel<<<N_EDGES, 256, 0, stream>>>(h8, eoff, enodes, s_e);
  egemm_kernel<<<N_EDGES, 128, 0, stream>>>(s_e, eoff, Wtf + 16384, mbf);
  node_gather_kernel<<<NG_BLOCKS, 256, 0, stream>>>(mbf, noff, nedges, hgb + 128, (uint32_t*)hA);
  // TB3: hA -> hB, TB4: hB -> out (fp32)
  gemm_kernel<false, 0><<<1024, 256, 0, stream>>>(hA, hB, WtTb + 3*49152, tbb + 3*384);
  gemm_kernel<false, 1><<<1024, 256, 0, stream>>>(hB, out, WtTb + 4*49152, tbb + 4*384);
}